// Round 2
// baseline (544.803 us; speedup 1.0000x reference)
//
#include <hip/hip_runtime.h>
#include <hip/hip_bf16.h>

#define B_ 32768
#define S_ 3
#define L_ 5
#define D1 32
#define D2 64
#define OUT_N 541
#define OUT_PAD 576
#define KDIM 320   // D2*L
#define EPS_ 1e-5f

typedef __attribute__((ext_vector_type(8))) short bf16x8;
typedef __attribute__((ext_vector_type(4))) float f32x4;

__device__ __forceinline__ short f2bf(float f) {
    __hip_bfloat16 h = __float2bfloat16(f);
    return *reinterpret_cast<short*>(&h);
}
__device__ __forceinline__ float bf2f(short u) {
    union { float f; unsigned v; } x;
    x.v = ((unsigned)(unsigned short)u) << 16;
    return x.f;
}

// tanh-form GELU: max abs deviation from exact-erf gelu ~3e-4.
__device__ __forceinline__ float gelu_fast(float x) {
    float x2 = x * x;
    float u = x * fmaf(x2, -0.0713548162726f, -1.59576912161f); // -2z
    float e = __expf(u);
    float r = __builtin_amdgcn_rcpf(1.0f + e);
    return x * r;
}

// ---------------------------------------------------------------------------
// Kernel 1: block = 256 threads = 32 b-values x 8 "ci" slots, one s.
// ---------------------------------------------------------------------------
__global__ __launch_bounds__(256, 3) void k_feat(
    const float* __restrict__ x, const float* __restrict__ w1, const float* __restrict__ b1,
    const float* __restrict__ w2, const float* __restrict__ b2,
    __hip_bfloat16* __restrict__ H, float* __restrict__ stats)
{
    const int s   = blockIdx.y;
    const int tid = threadIdx.x;
    const int ci  = tid & 7;
    const int bi  = tid >> 3;
    const int b   = blockIdx.x * 32 + bi;

    __shared__ __align__(16) float sw1[D1 * 3];
    __shared__ float sb1[D1];
    __shared__ __align__(16) float sw2T[D1 * 3 * D2];   // [c1][dl][c2]
    __shared__ float sb2[D2];
    __shared__ __align__(16) short sh1[32 * 264];       // [bi][c1*8]
    __shared__ float sred[4][8][16];

    // hoist x loads: overlap global latency with LDS weight staging
    float xv[L_ + 2];
    xv[0] = 0.f; xv[L_ + 1] = 0.f;
    const float* xp = x + (size_t)b * (S_ * L_) + s * L_;
#pragma unroll
    for (int l = 0; l < L_; ++l) xv[l + 1] = xp[l];

    for (int i = tid; i < D1 * 3; i += 256) sw1[i] = w1[s * D1 * 3 + i];
    for (int i = tid; i < D1; i += 256)     sb1[i] = b1[s * D1 + i];
    for (int i = tid; i < D2; i += 256)     sb2[i] = b2[s * D2 + i];
    for (int i = tid; i < D1 * 3 * D2; i += 256) {
        int c2 = i & 63, t = i >> 6;
        int dl = t % 3, c1 = t / 3;
        sw2T[i] = w2[((size_t)(s * D2 + c2) * D1 + c1) * 3 + dl];
    }
    __syncthreads();

    // ---- Phase 1: conv1 + gelu for 4 channels of this bi ----
#pragma unroll
    for (int k = 0; k < 4; ++k) {
        const int c1 = ci * 4 + k;
        const float wa = sw1[c1 * 3 + 0], wb = sw1[c1 * 3 + 1], wc = sw1[c1 * 3 + 2];
        const float bb = sb1[c1];
        bf16x8 pk;
#pragma unroll
        for (int l = 0; l < L_; ++l) {
            float v = fmaf(wa, xv[l], fmaf(wb, xv[l + 1], fmaf(wc, xv[l + 2], bb)));
            pk[l] = f2bf(gelu_fast(v));
        }
        pk[5] = 0; pk[6] = 0; pk[7] = 0;
        *(bf16x8*)&sh1[bi * 264 + c1 * 8] = pk;
    }
    __syncthreads();

    // ---- Phase 2: conv2 + gelu for 8 channels c2 = ci*8 + j ----
    float acc[8][5];
#pragma unroll
    for (int j = 0; j < 8; ++j) {
        const float bb = sb2[ci * 8 + j];
#pragma unroll
        for (int l = 0; l < 5; ++l) acc[j][l] = bb;
    }

#pragma unroll 2
    for (int c1 = 0; c1 < D1; ++c1) {
        bf16x8 hv = *(const bf16x8*)&sh1[bi * 264 + c1 * 8];
        const float p0 = bf2f(hv[0]), p1 = bf2f(hv[1]), p2 = bf2f(hv[2]),
                    p3 = bf2f(hv[3]), p4 = bf2f(hv[4]);
        const float* wbase = &sw2T[c1 * 3 * 64 + ci * 8];
        f32x4 w0a = *(const f32x4*)(wbase + 0 * 64);
        f32x4 w0b = *(const f32x4*)(wbase + 0 * 64 + 4);
        f32x4 w1a = *(const f32x4*)(wbase + 1 * 64);
        f32x4 w1b = *(const f32x4*)(wbase + 1 * 64 + 4);
        f32x4 w2a = *(const f32x4*)(wbase + 2 * 64);
        f32x4 w2b = *(const f32x4*)(wbase + 2 * 64 + 4);
#pragma unroll
        for (int j = 0; j < 8; ++j) {
            const float wA = (j < 4) ? w0a[j & 3] : w0b[j & 3];
            const float wB = (j < 4) ? w1a[j & 3] : w1b[j & 3];
            const float wC = (j < 4) ? w2a[j & 3] : w2b[j & 3];
            acc[j][0] = fmaf(wB, p0, fmaf(wC, p1, acc[j][0]));
            acc[j][1] = fmaf(wA, p0, fmaf(wB, p1, fmaf(wC, p2, acc[j][1])));
            acc[j][2] = fmaf(wA, p1, fmaf(wB, p2, fmaf(wC, p3, acc[j][2])));
            acc[j][3] = fmaf(wA, p2, fmaf(wB, p3, fmaf(wC, p4, acc[j][3])));
            acc[j][4] = fmaf(wA, p3, fmaf(wB, p4, acc[j][4]));
        }
    }

    // gelu, quantize, stats, store
    bf16x8 hbv[5];
    float su[8], sq[8];
#pragma unroll
    for (int j = 0; j < 8; ++j) { su[j] = 0.f; sq[j] = 0.f; }
#pragma unroll
    for (int t = 0; t < 5; ++t) {
#pragma unroll
        for (int e = 0; e < 8; ++e) {
            const int idx = t * 8 + e;
            const int j = idx / 5, l = idx % 5;
            float g = gelu_fast(acc[j][l]);
            short hb = f2bf(g);
            hbv[t][e] = hb;
            float gq = bf2f(hb);
            su[j] += gq;
            sq[j] = fmaf(gq, gq, sq[j]);
        }
    }
    bf16x8* dst = (bf16x8*)(H + ((size_t)s * B_ + b) * KDIM + ci * 40);
#pragma unroll
    for (int t = 0; t < 5; ++t) dst[t] = hbv[t];

#pragma unroll
    for (int j = 0; j < 8; ++j) {
        su[j] += __shfl_down(su[j], 32); sq[j] += __shfl_down(sq[j], 32);
        su[j] += __shfl_down(su[j], 16); sq[j] += __shfl_down(sq[j], 16);
        su[j] += __shfl_down(su[j], 8);  sq[j] += __shfl_down(sq[j], 8);
    }
    const int wid = tid >> 6;
    const int lane = tid & 63;
    if (lane < 8) {
#pragma unroll
        for (int j = 0; j < 8; ++j) {
            sred[wid][lane][j] = su[j];
            sred[wid][lane][8 + j] = sq[j];
        }
    }
    __syncthreads();
    if (tid < 128) {
        const int which = tid >> 6;
        const int c2 = tid & 63;
        const int rci = c2 >> 3, rj = c2 & 7;
        float v = sred[0][rci][which * 8 + rj] + sred[1][rci][which * 8 + rj]
                + sred[2][rci][which * 8 + rj] + sred[3][rci][which * 8 + rj];
        atomicAdd(&stats[(s * D2 + c2) * 2 + which], v);
    }
}

// ---------------------------------------------------------------------------
__global__ void k_stats(const float* __restrict__ stats,
                        const float* __restrict__ gamma, const float* __restrict__ beta,
                        float* __restrict__ af, float* __restrict__ cf)
{
    int i = threadIdx.x;
    if (i < S_ * D2) {
        const float n = (float)B_ * (float)L_;
        float su = stats[i * 2 + 0], sq = stats[i * 2 + 1];
        float mean = su / n;
        float var = sq / n - mean * mean;
        float rstd = rsqrtf(var + EPS_);
        float a = gamma[i] * rstd;
        af[i] = a;
        cf[i] = beta[i] - mean * a;
    }
}

// ---------------------------------------------------------------------------
__global__ __launch_bounds__(64) void k_fold(
    const float* __restrict__ wl, const float* __restrict__ bl,
    const float* __restrict__ af, const float* __restrict__ cf,
    __hip_bfloat16* __restrict__ Wp, float* __restrict__ blp)
{
    const int row = blockIdx.x;
    const int s = row / OUT_PAD, o = row % OUT_PAD;
    const int lane = threadIdx.x;
    __hip_bfloat16* wrow = Wp + (size_t)row * KDIM;
    if (o >= OUT_N) {
#pragma unroll
        for (int t = 0; t < 5; ++t) wrow[lane * 5 + t] = __float2bfloat16(0.f);
        if (lane == 0) blp[row] = 0.f;
        return;
    }
    const float* wsrc = wl + ((size_t)s * OUT_N + o) * KDIM;
    const float a = af[s * D2 + lane];
    const float c = cf[s * D2 + lane];
    float bacc = 0.f;
#pragma unroll
    for (int t = 0; t < 5; ++t) {
        float wv = wsrc[lane * 5 + t];
        wrow[lane * 5 + t] = __float2bfloat16(wv * a);
        bacc = fmaf(wv, c, bacc);
    }
#pragma unroll
    for (int off = 32; off > 0; off >>= 1) bacc += __shfl_down(bacc, off);
    if (lane == 0) blp[row] = bacc + bl[s * OUT_N + o];
}

// ---------------------------------------------------------------------------
// Kernel 3 v4: barrier-free bf16 MFMA GEMM.
//   M is wave-private (M-split block) -> LDS staging of A had zero cross-wave
//   reuse; it only bought barriers (vmcnt(0) drains) + 32KB LDS occupancy cap.
//   v4: A and B fragments load direct global->VGPR (16B/lane dwordx4),
//   tile 256M x 64N per block (wave = 64 rows, mt=4 -> 4x register reuse of B
//   frags), zero LDS, zero __syncthreads. Latency hidden by 16 waves/CU + full
//   K unroll (compiler hoists loads, waves slip freely).
// ---------------------------------------------------------------------------
__global__ __launch_bounds__(256, 4) void k_gemm(
    const __hip_bfloat16* __restrict__ H, const __hip_bfloat16* __restrict__ Wp,
    const float* __restrict__ blp, float* __restrict__ out)
{
    const int s    = blockIdx.z;
    const int bm   = blockIdx.x * 256;
    const int bn   = blockIdx.y * 64;
    const int tid  = threadIdx.x;
    const int wave = tid >> 6;
    const int lane = tid & 63;
    const int lm   = lane & 15;
    const int quad = lane >> 4;

    const short* Hs = (const short*)H + (size_t)s * B_ * KDIM;
    const short* Bp = (const short*)Wp + ((size_t)s * OUT_PAD + bn) * KDIM;

    // A: row = bm + wave*64 + mt*16 + lm, k = c*64 + s2*32 + quad*8
    const short* Ap = Hs + (size_t)(bm + wave * 64 + lm) * KDIM + quad * 8;
    // B: row (=out col) = bn + nt*16 + lm, same k
    const short* Bq = Bp + (size_t)lm * KDIM + quad * 8;

    f32x4 acc[4][4];
#pragma unroll
    for (int mt = 0; mt < 4; ++mt)
#pragma unroll
        for (int nt = 0; nt < 4; ++nt) acc[mt][nt] = (f32x4){0.f, 0.f, 0.f, 0.f};

#pragma unroll
    for (int c = 0; c < 5; ++c) {
#pragma unroll
        for (int s2 = 0; s2 < 2; ++s2) {
            const int ko = c * 64 + s2 * 32;
            bf16x8 bfr[4];
#pragma unroll
            for (int nt = 0; nt < 4; ++nt)
                bfr[nt] = *(const bf16x8*)(Bq + (size_t)nt * 16 * KDIM + ko);
            bf16x8 afr[4];
#pragma unroll
            for (int mt = 0; mt < 4; ++mt)
                afr[mt] = *(const bf16x8*)(Ap + (size_t)mt * 16 * KDIM + ko);
#pragma unroll
            for (int mt = 0; mt < 4; ++mt)
#pragma unroll
                for (int nt = 0; nt < 4; ++nt)
                    acc[mt][nt] = __builtin_amdgcn_mfma_f32_16x16x32_bf16(
                        afr[mt], bfr[nt], acc[mt][nt], 0, 0, 0);
        }
    }

    // epilogue: C layout col = lane&15, row = quad*4 + r
#pragma unroll
    for (int nt = 0; nt < 4; ++nt) {
        const int col = bn + nt * 16 + lm;
        if (col < OUT_N) {
            const float bias = blp[s * OUT_PAD + col];
#pragma unroll
            for (int mt = 0; mt < 4; ++mt) {
                const int row0 = bm + wave * 64 + mt * 16 + quad * 4;
#pragma unroll
                for (int r = 0; r < 4; ++r) {
                    out[((size_t)(row0 + r) * S_ + s) * OUT_N + col] = acc[mt][nt][r] + bias;
                }
            }
        }
    }
}

// ---------------------------------------------------------------------------
extern "C" void kernel_launch(void* const* d_in, const int* in_sizes, int n_in,
                              void* d_out, int out_size, void* d_ws, size_t ws_size,
                              hipStream_t stream) {
    const float* x     = (const float*)d_in[0];
    const float* w1    = (const float*)d_in[1];
    const float* b1    = (const float*)d_in[2];
    const float* w2    = (const float*)d_in[3];
    const float* b2    = (const float*)d_in[4];
    const float* gamma = (const float*)d_in[5];
    const float* beta  = (const float*)d_in[6];
    const float* wl    = (const float*)d_in[7];
    const float* bl    = (const float*)d_in[8];
    float* out = (float*)d_out;

    char* ws = (char*)d_ws;
    __hip_bfloat16* H = (__hip_bfloat16*)ws;
    size_t offH = (size_t)S_ * B_ * KDIM * sizeof(__hip_bfloat16);
    float* stats = (float*)(ws + offH);
    float* af = stats + S_ * D2 * 2;
    float* cf = af + S_ * D2;
    __hip_bfloat16* Wp = (__hip_bfloat16*)(cf + S_ * D2);
    float* blp = (float*)((char*)Wp + (size_t)S_ * OUT_PAD * KDIM * sizeof(__hip_bfloat16));

    hipMemsetAsync(stats, 0, (size_t)S_ * D2 * 2 * sizeof(float), stream);

    k_feat<<<dim3(B_ / 32, S_), 256, 0, stream>>>(x, w1, b1, w2, b2, H, stats);
    k_stats<<<1, 256, 0, stream>>>(stats, gamma, beta, af, cf);
    k_fold<<<S_ * OUT_PAD, 64, 0, stream>>>(wl, bl, af, cf, Wp, blp);
    k_gemm<<<dim3(B_ / 256, OUT_PAD / 64, S_), 256, 0, stream>>>(H, Wp, blp, out);
}

// Round 3
// 441.715 us; speedup vs baseline: 1.2334x; 1.2334x over previous
//
#include <hip/hip_runtime.h>
#include <hip/hip_bf16.h>

#define B_ 32768
#define S_ 3
#define L_ 5
#define D1 32
#define D2 64
#define OUT_N 541
#define OUT_PAD 576
#define KDIM 320   // D2*L
#define EPS_ 1e-5f

typedef __attribute__((ext_vector_type(8))) short bf16x8;
typedef __attribute__((ext_vector_type(4))) float f32x4;

__device__ __forceinline__ short f2bf(float f) {
    __hip_bfloat16 h = __float2bfloat16(f);
    return *reinterpret_cast<short*>(&h);
}
__device__ __forceinline__ float bf2f(short u) {
    union { float f; unsigned v; } x;
    x.v = ((unsigned)(unsigned short)u) << 16;
    return x.f;
}

// tanh-form GELU: max abs deviation from exact-erf gelu ~3e-4.
__device__ __forceinline__ float gelu_fast(float x) {
    float x2 = x * x;
    float u = x * fmaf(x2, -0.0713548162726f, -1.59576912161f); // -2z
    float e = __expf(u);
    float r = __builtin_amdgcn_rcpf(1.0f + e);
    return x * r;
}

// async 16B global -> LDS
__device__ __forceinline__ void cp16(void* lds, const void* g) {
    __builtin_amdgcn_global_load_lds(
        (const __attribute__((address_space(1))) unsigned int*)g,
        (__attribute__((address_space(3))) unsigned int*)lds, 16, 0, 0);
}

// ---------------------------------------------------------------------------
// Kernel 1: block = 256 threads = 32 b-values x 8 "ci" slots, one s.
// ---------------------------------------------------------------------------
__global__ __launch_bounds__(256, 3) void k_feat(
    const float* __restrict__ x, const float* __restrict__ w1, const float* __restrict__ b1,
    const float* __restrict__ w2, const float* __restrict__ b2,
    __hip_bfloat16* __restrict__ H, float* __restrict__ stats)
{
    const int s   = blockIdx.y;
    const int tid = threadIdx.x;
    const int ci  = tid & 7;
    const int bi  = tid >> 3;
    const int b   = blockIdx.x * 32 + bi;

    __shared__ __align__(16) float sw1[D1 * 3];
    __shared__ float sb1[D1];
    __shared__ __align__(16) float sw2T[D1 * 3 * D2];   // [c1][dl][c2]
    __shared__ float sb2[D2];
    __shared__ __align__(16) short sh1[32 * 264];       // [bi][c1*8]
    __shared__ float sred[4][8][16];

    // hoist x loads: overlap global latency with LDS weight staging
    float xv[L_ + 2];
    xv[0] = 0.f; xv[L_ + 1] = 0.f;
    const float* xp = x + (size_t)b * (S_ * L_) + s * L_;
#pragma unroll
    for (int l = 0; l < L_; ++l) xv[l + 1] = xp[l];

    for (int i = tid; i < D1 * 3; i += 256) sw1[i] = w1[s * D1 * 3 + i];
    for (int i = tid; i < D1; i += 256)     sb1[i] = b1[s * D1 + i];
    for (int i = tid; i < D2; i += 256)     sb2[i] = b2[s * D2 + i];
    for (int i = tid; i < D1 * 3 * D2; i += 256) {
        int c2 = i & 63, t = i >> 6;
        int dl = t % 3, c1 = t / 3;
        sw2T[i] = w2[((size_t)(s * D2 + c2) * D1 + c1) * 3 + dl];
    }
    __syncthreads();

    // ---- Phase 1: conv1 + gelu for 4 channels of this bi ----
#pragma unroll
    for (int k = 0; k < 4; ++k) {
        const int c1 = ci * 4 + k;
        const float wa = sw1[c1 * 3 + 0], wb = sw1[c1 * 3 + 1], wc = sw1[c1 * 3 + 2];
        const float bb = sb1[c1];
        bf16x8 pk;
#pragma unroll
        for (int l = 0; l < L_; ++l) {
            float v = fmaf(wa, xv[l], fmaf(wb, xv[l + 1], fmaf(wc, xv[l + 2], bb)));
            pk[l] = f2bf(gelu_fast(v));
        }
        pk[5] = 0; pk[6] = 0; pk[7] = 0;
        *(bf16x8*)&sh1[bi * 264 + c1 * 8] = pk;
    }
    __syncthreads();

    // ---- Phase 2: conv2 + gelu for 8 channels c2 = ci*8 + j ----
    float acc[8][5];
#pragma unroll
    for (int j = 0; j < 8; ++j) {
        const float bb = sb2[ci * 8 + j];
#pragma unroll
        for (int l = 0; l < 5; ++l) acc[j][l] = bb;
    }

#pragma unroll 2
    for (int c1 = 0; c1 < D1; ++c1) {
        bf16x8 hv = *(const bf16x8*)&sh1[bi * 264 + c1 * 8];
        const float p0 = bf2f(hv[0]), p1 = bf2f(hv[1]), p2 = bf2f(hv[2]),
                    p3 = bf2f(hv[3]), p4 = bf2f(hv[4]);
        const float* wbase = &sw2T[c1 * 3 * 64 + ci * 8];
        f32x4 w0a = *(const f32x4*)(wbase + 0 * 64);
        f32x4 w0b = *(const f32x4*)(wbase + 0 * 64 + 4);
        f32x4 w1a = *(const f32x4*)(wbase + 1 * 64);
        f32x4 w1b = *(const f32x4*)(wbase + 1 * 64 + 4);
        f32x4 w2a = *(const f32x4*)(wbase + 2 * 64);
        f32x4 w2b = *(const f32x4*)(wbase + 2 * 64 + 4);
#pragma unroll
        for (int j = 0; j < 8; ++j) {
            const float wA = (j < 4) ? w0a[j & 3] : w0b[j & 3];
            const float wB = (j < 4) ? w1a[j & 3] : w1b[j & 3];
            const float wC = (j < 4) ? w2a[j & 3] : w2b[j & 3];
            acc[j][0] = fmaf(wB, p0, fmaf(wC, p1, acc[j][0]));
            acc[j][1] = fmaf(wA, p0, fmaf(wB, p1, fmaf(wC, p2, acc[j][1])));
            acc[j][2] = fmaf(wA, p1, fmaf(wB, p2, fmaf(wC, p3, acc[j][2])));
            acc[j][3] = fmaf(wA, p2, fmaf(wB, p3, fmaf(wC, p4, acc[j][3])));
            acc[j][4] = fmaf(wA, p3, fmaf(wB, p4, acc[j][4]));
        }
    }

    // gelu, quantize, stats, store
    bf16x8 hbv[5];
    float su[8], sq[8];
#pragma unroll
    for (int j = 0; j < 8; ++j) { su[j] = 0.f; sq[j] = 0.f; }
#pragma unroll
    for (int t = 0; t < 5; ++t) {
#pragma unroll
        for (int e = 0; e < 8; ++e) {
            const int idx = t * 8 + e;
            const int j = idx / 5, l = idx % 5;
            float g = gelu_fast(acc[j][l]);
            short hb = f2bf(g);
            hbv[t][e] = hb;
            float gq = bf2f(hb);
            su[j] += gq;
            sq[j] = fmaf(gq, gq, sq[j]);
        }
    }
    bf16x8* dst = (bf16x8*)(H + ((size_t)s * B_ + b) * KDIM + ci * 40);
#pragma unroll
    for (int t = 0; t < 5; ++t) dst[t] = hbv[t];

#pragma unroll
    for (int j = 0; j < 8; ++j) {
        su[j] += __shfl_down(su[j], 32); sq[j] += __shfl_down(sq[j], 32);
        su[j] += __shfl_down(su[j], 16); sq[j] += __shfl_down(sq[j], 16);
        su[j] += __shfl_down(su[j], 8);  sq[j] += __shfl_down(sq[j], 8);
    }
    const int wid = tid >> 6;
    const int lane = tid & 63;
    if (lane < 8) {
#pragma unroll
        for (int j = 0; j < 8; ++j) {
            sred[wid][lane][j] = su[j];
            sred[wid][lane][8 + j] = sq[j];
        }
    }
    __syncthreads();
    if (tid < 128) {
        const int which = tid >> 6;
        const int c2 = tid & 63;
        const int rci = c2 >> 3, rj = c2 & 7;
        float v = sred[0][rci][which * 8 + rj] + sred[1][rci][which * 8 + rj]
                + sred[2][rci][which * 8 + rj] + sred[3][rci][which * 8 + rj];
        atomicAdd(&stats[(s * D2 + c2) * 2 + which], v);
    }
}

// ---------------------------------------------------------------------------
__global__ void k_stats(const float* __restrict__ stats,
                        const float* __restrict__ gamma, const float* __restrict__ beta,
                        float* __restrict__ af, float* __restrict__ cf)
{
    int i = threadIdx.x;
    if (i < S_ * D2) {
        const float n = (float)B_ * (float)L_;
        float su = stats[i * 2 + 0], sq = stats[i * 2 + 1];
        float mean = su / n;
        float var = sq / n - mean * mean;
        float rstd = rsqrtf(var + EPS_);
        float a = gamma[i] * rstd;
        af[i] = a;
        cf[i] = beta[i] - mean * a;
    }
}

// ---------------------------------------------------------------------------
// k_fold v2: emit Wp in [s][kstep(10)][quad(4)][col(576)][8] bf16 layout so a
// k_gemm B-fragment load is 4 contiguous 256B segments per wave (was 16x64B).
// Rows o >= OUT_N are zeroed (MFMA on them is harmless, stores are masked).
// ---------------------------------------------------------------------------
__global__ __launch_bounds__(64) void k_fold(
    const float* __restrict__ wl, const float* __restrict__ bl,
    const float* __restrict__ af, const float* __restrict__ cf,
    __hip_bfloat16* __restrict__ Wp, float* __restrict__ blp)
{
    const int row = blockIdx.x;
    const int s = row / OUT_PAD, o = row % OUT_PAD;
    const int lane = threadIdx.x;
    short* Wb = (short*)Wp + (size_t)s * 40 * 576 * 8;   // s plane

    if (o >= OUT_N) {
#pragma unroll
        for (int t = 0; t < 5; ++t) {
            const int k = lane * 5 + t;
            const int idx = (((k >> 5) * 4 + ((k >> 3) & 3)) * 576 + o) * 8 + (k & 7);
            Wb[idx] = f2bf(0.f);
        }
        if (lane == 0) blp[row] = 0.f;
        return;
    }
    const float* wsrc = wl + ((size_t)s * OUT_N + o) * KDIM;
    const float a = af[s * D2 + lane];   // k = lane*5+t -> channel = lane
    const float c = cf[s * D2 + lane];
    float bacc = 0.f;
#pragma unroll
    for (int t = 0; t < 5; ++t) {
        const int k = lane * 5 + t;
        float wv = wsrc[k];
        const int idx = (((k >> 5) * 4 + ((k >> 3) & 3)) * 576 + o) * 8 + (k & 7);
        Wb[idx] = f2bf(wv * a);
        bacc = fmaf(wv, c, bacc);
    }
#pragma unroll
    for (int off = 32; off > 0; off >>= 1) bacc += __shfl_down(bacc, off);
    if (lane == 0) blp[row] = bacc + bl[s * OUT_N + o];
}

// ---------------------------------------------------------------------------
// Kernel 3 v5: full-N blocks, write-coalescing-first GEMM.
//   Evidence (r2): dur tracks WRITE_SIZE (330MB @1.46TB/s), not FETCH; all
//   pipes <8% busy. out rows (2164B) were split across 9 bn-blocks -> partial
//   128B lines -> 1.55x write amplification + scattered-store serialization.
//   v5: block = 32M x 576N (full row), wave = 32M x 144N. A-panel (20KB) LDS-
//   staged once (XOR-swizzled, pre-swizzled global src), ONE barrier, 10
//   unrolled K-steps, B direct from L2 in the k_fold-transposed layout.
//   Epilogue: per row, 9 sequential 64B chunks from one wave -> full lines.
//   A is fetched exactly once (63MB total, no 9x bn re-read).
// ---------------------------------------------------------------------------
__global__ __launch_bounds__(256, 3) void k_gemm(
    const __hip_bfloat16* __restrict__ H, const __hip_bfloat16* __restrict__ Wp,
    const float* __restrict__ blp, float* __restrict__ out)
{
    const int s    = blockIdx.z;
    const int bm   = blockIdx.x * 32;
    const int tid  = threadIdx.x;
    const int wave = tid >> 6;
    const int lane = tid & 63;
    const int lm   = lane & 15;
    const int quad = lane >> 4;

    __shared__ __align__(16) short sA[32 * 320];   // [row][16B-chunk, XOR-swizzled]

    const short* Hs = (const short*)H + (size_t)s * B_ * KDIM;

    // stage A panel: 1280 chunks of 16B; linear LDS dest (global_load_lds
    // constraint), inverse-swizzled global source (m173 pattern).
#pragma unroll
    for (int i = 0; i < 5; ++i) {
        const int f = i * 256 + tid;              // 0..1279
        const int row = f / 40, cslot = f % 40;
        const int cg = (cslot & ~7) | ((cslot & 7) ^ (row & 7));
        cp16(&sA[f * 8], Hs + (size_t)(bm + row) * KDIM + cg * 8);
    }
    __syncthreads();   // the only barrier

    const short* Bs = (const short*)Wp + (size_t)s * 40 * 576 * 8;
    const int colw = wave * 144;

    f32x4 acc[2][9];
#pragma unroll
    for (int mt = 0; mt < 2; ++mt)
#pragma unroll
        for (int nt = 0; nt < 9; ++nt) acc[mt][nt] = (f32x4){0.f, 0.f, 0.f, 0.f};

#pragma unroll
    for (int ks = 0; ks < 10; ++ks) {
        bf16x8 bfr[9];
#pragma unroll
        for (int nt = 0; nt < 9; ++nt) {
            // [ks][quad][col][8]: lanes lm contiguous -> 4x256B segments/wave
            bfr[nt] = *(const bf16x8*)(Bs +
                ((size_t)(ks * 4 + quad) * 576 + colw + nt * 16 + lm) * 8);
        }
#pragma unroll
        for (int mt = 0; mt < 2; ++mt) {
            const int row = mt * 16 + lm;
            const int chunk = ks * 4 + quad;
            const int swz = (chunk & ~7) | ((chunk & 7) ^ (row & 7));
            bf16x8 af = *(const bf16x8*)&sA[row * 320 + swz * 8];
#pragma unroll
            for (int nt = 0; nt < 9; ++nt)
                acc[mt][nt] = __builtin_amdgcn_mfma_f32_16x16x32_bf16(
                    af, bfr[nt], acc[mt][nt], 0, 0, 0);
        }
    }

    // epilogue: bias + store. Per row: 9 sequential 64B chunks (nt inner).
    float bias[9];
#pragma unroll
    for (int nt = 0; nt < 9; ++nt) bias[nt] = blp[s * OUT_PAD + colw + nt * 16 + lm];

#pragma unroll
    for (int mt = 0; mt < 2; ++mt) {
#pragma unroll
        for (int r = 0; r < 4; ++r) {
            const int row = bm + mt * 16 + quad * 4 + r;
            float* orow = out + ((size_t)row * S_ + s) * OUT_N;
#pragma unroll
            for (int nt = 0; nt < 9; ++nt) {
                const int col = colw + nt * 16 + lm;
                if (col < OUT_N) orow[col] = acc[mt][nt][r] + bias[nt];
            }
        }
    }
}

// ---------------------------------------------------------------------------
extern "C" void kernel_launch(void* const* d_in, const int* in_sizes, int n_in,
                              void* d_out, int out_size, void* d_ws, size_t ws_size,
                              hipStream_t stream) {
    const float* x     = (const float*)d_in[0];
    const float* w1    = (const float*)d_in[1];
    const float* b1    = (const float*)d_in[2];
    const float* w2    = (const float*)d_in[3];
    const float* b2    = (const float*)d_in[4];
    const float* gamma = (const float*)d_in[5];
    const float* beta  = (const float*)d_in[6];
    const float* wl    = (const float*)d_in[7];
    const float* bl    = (const float*)d_in[8];
    float* out = (float*)d_out;

    char* ws = (char*)d_ws;
    __hip_bfloat16* H = (__hip_bfloat16*)ws;
    size_t offH = (size_t)S_ * B_ * KDIM * sizeof(__hip_bfloat16);
    float* stats = (float*)(ws + offH);
    float* af = stats + S_ * D2 * 2;
    float* cf = af + S_ * D2;
    __hip_bfloat16* Wp = (__hip_bfloat16*)(cf + S_ * D2);
    float* blp = (float*)((char*)Wp + (size_t)S_ * OUT_PAD * KDIM * sizeof(__hip_bfloat16));

    hipMemsetAsync(stats, 0, (size_t)S_ * D2 * 2 * sizeof(float), stream);

    k_feat<<<dim3(B_ / 32, S_), 256, 0, stream>>>(x, w1, b1, w2, b2, H, stats);
    k_stats<<<1, 256, 0, stream>>>(stats, gamma, beta, af, cf);
    k_fold<<<S_ * OUT_PAD, 64, 0, stream>>>(wl, bl, af, cf, Wp, blp);
    k_gemm<<<dim3(B_ / 32, 1, S_), 256, 0, stream>>>(H, Wp, blp, out);
}

// Round 5
// 413.453 us; speedup vs baseline: 1.3177x; 1.0684x over previous
//
#include <hip/hip_runtime.h>
#include <hip/hip_bf16.h>

#define B_ 32768
#define S_ 3
#define L_ 5
#define D1 32
#define D2 64
#define OUT_N 541
#define OUT_PAD 576
#define KDIM 320   // D2*L
#define EPS_ 1e-5f

typedef __attribute__((ext_vector_type(8))) short bf16x8;
typedef __attribute__((ext_vector_type(4))) short bf16x4;
typedef __attribute__((ext_vector_type(4))) float f32x4;

__device__ __forceinline__ short f2bf(float f) {
    __hip_bfloat16 h = __float2bfloat16(f);
    return *reinterpret_cast<short*>(&h);
}
__device__ __forceinline__ float bf2f(short u) {
    union { float f; unsigned v; } x;
    x.v = ((unsigned)(unsigned short)u) << 16;
    return x.f;
}

// tanh-form GELU: max abs deviation from exact-erf gelu ~3e-4.
__device__ __forceinline__ float gelu_fast(float x) {
    float x2 = x * x;
    float u = x * fmaf(x2, -0.0713548162726f, -1.59576912161f); // -2z
    float e = __expf(u);
    float r = __builtin_amdgcn_rcpf(1.0f + e);
    return x * r;
}

// async 16B global -> LDS
__device__ __forceinline__ void cp16(void* lds, const void* g) {
    __builtin_amdgcn_global_load_lds(
        (const __attribute__((address_space(1))) unsigned int*)g,
        (__attribute__((address_space(3))) unsigned int*)lds, 16, 0, 0);
}

// ---------------------------------------------------------------------------
// Kernel 1 v7: MFMA conv2, de-risked rewrite of failed v6.
//   v6 failed correctness (absmax 1.9); derivation of all index maps checks
//   against the conventions pinned by the PASSING v5 k_gemm, so v7 removes
//   every novel construct instead: (1) NO LDS union (dedicated sh1T/sw2B/sh2,
//   50.7KB, 3 blk/CU); (2) NO guarded MFMAs -- h1 zero-padded in l (7 slabs,
//   stride 232 shorts: 232=116dw, 116%32=20 -> 2-way-free bank pattern);
//   (3) stats + H-store are v5's PROVEN epilogue verbatim, sourced from sh2.
//   Novel surface: phase-1 layout, 30 unconditional MFMAs, quantize-repack.
// ---------------------------------------------------------------------------
__global__ __launch_bounds__(256, 3) void k_feat(
    const float* __restrict__ x, const float* __restrict__ w1, const float* __restrict__ b1,
    const float* __restrict__ w2, const float* __restrict__ b2,
    __hip_bfloat16* __restrict__ H, float* __restrict__ stats)
{
    const int s   = blockIdx.y;
    const int tid = threadIdx.x;
    const int ci  = tid & 7;
    const int bi  = tid >> 3;
    const int b   = blockIdx.x * 32 + bi;

    const int wave = tid >> 6;
    const int lane = tid & 63;
    const int lm   = lane & 15;
    const int quad = lane >> 4;

    __shared__ __align__(16) short sh1T[32 * 232];    // [b][lpad(7)][c1(32)] +8 pad
    __shared__ __align__(16) short sw2B[3 * 64 * 32]; // [dl][c2][c1]
    __shared__ __align__(16) short sh2[32 * 328];     // [b][c2*5+l] +8 pad
    __shared__ float sw1[D1 * 3];
    __shared__ float sb1[D1];
    __shared__ float sred[4][8][16];

    // hoist x loads
    float xv[L_ + 2];
    xv[0] = 0.f; xv[L_ + 1] = 0.f;
    const float* xp = x + (size_t)b * (S_ * L_) + s * L_;
#pragma unroll
    for (int l = 0; l < L_; ++l) xv[l + 1] = xp[l];

    // per-lane conv2 bias (c2 = wave*16+lm)
    const float bc = b2[s * D2 + wave * 16 + lm];

    // stage w1/b1 fp32; w2 -> bf16 sw2B[dl][c2][c1]  (t = i/3 = c2*32+c1)
    for (int i = tid; i < D1 * 3; i += 256) sw1[i] = w1[s * D1 * 3 + i];
    for (int i = tid; i < D1; i += 256)     sb1[i] = b1[s * D1 + i];
    for (int i = tid; i < D1 * 3 * D2; i += 256) {
        const int dl = i % 3, t = i / 3;
        sw2B[dl * 2048 + t] = f2bf(w2[s * D1 * 3 * D2 + i]);
    }
    __syncthreads();

    // ---- Phase 1: conv1 + gelu -> sh1T[b][l+1][c1]; zero pad slabs l=0,6 ----
    float wk0[4], wk1[4], wk2[4], bk[4];
#pragma unroll
    for (int k = 0; k < 4; ++k) {
        const int c1 = ci * 4 + k;
        wk0[k] = sw1[c1 * 3 + 0]; wk1[k] = sw1[c1 * 3 + 1]; wk2[k] = sw1[c1 * 3 + 2];
        bk[k] = sb1[c1];
    }
    const bf16x4 z4 = (bf16x4){0, 0, 0, 0};
    *(bf16x4*)&sh1T[bi * 232 + 0 * 32 + ci * 4] = z4;
    *(bf16x4*)&sh1T[bi * 232 + 6 * 32 + ci * 4] = z4;
#pragma unroll
    for (int l = 0; l < L_; ++l) {
        bf16x4 pk;
#pragma unroll
        for (int k = 0; k < 4; ++k) {
            float v = fmaf(wk0[k], xv[l], fmaf(wk1[k], xv[l + 1], fmaf(wk2[k], xv[l + 2], bk[k])));
            pk[k] = f2bf(gelu_fast(v));
        }
        *(bf16x4*)&sh1T[bi * 232 + (l + 1) * 32 + ci * 4] = pk;
    }
    __syncthreads();

    // ---- Phase 2: 30 unconditional MFMAs ----
    // B-frag: lane (n=lm -> c2 = wave*16+lm, kblock=quad -> c1 = quad*8+e)
    bf16x8 bfr[3];
#pragma unroll
    for (int dl = 0; dl < 3; ++dl)
        bfr[dl] = *(const bf16x8*)&sw2B[dl * 2048 + (wave * 16 + lm) * 32 + quad * 8];

    f32x4 acc[10];
#pragma unroll
    for (int mt = 0; mt < 10; ++mt) acc[mt] = (f32x4){bc, bc, bc, bc};

#pragma unroll
    for (int mt = 0; mt < 10; ++mt) {
        const int l  = mt >> 1;                 // output l
        const int bb = (mt & 1) * 16 + lm;      // A-row = b index (m = lm)
#pragma unroll
        for (int dl = 0; dl < 3; ++dl) {
            // padded slab index l+dl in [0,6]; pad slabs are zero
            bf16x8 af = *(const bf16x8*)&sh1T[bb * 232 + (l + dl) * 32 + quad * 8];
            acc[mt] = __builtin_amdgcn_mfma_f32_16x16x32_bf16(af, bfr[dl], acc[mt], 0, 0, 0);
        }
    }

    // ---- quantize + repack to sh2[b][c2*5+l] (D: row=quad*4+r, col=lm) ----
    const int c2w = wave * 16 + lm;
#pragma unroll
    for (int mt = 0; mt < 10; ++mt) {
        const int l = mt >> 1;
#pragma unroll
        for (int r = 0; r < 4; ++r) {
            const int bb = (mt & 1) * 16 + quad * 4 + r;
            sh2[bb * 328 + c2w * 5 + l] = f2bf(gelu_fast(acc[mt][r]));
        }
    }
    __syncthreads();

    // ---- epilogue: v5-verbatim stats + coalesced H store, sourced from sh2 ----
    bf16x8 hbv[5];
    float su[8], sq[8];
#pragma unroll
    for (int j = 0; j < 8; ++j) { su[j] = 0.f; sq[j] = 0.f; }
#pragma unroll
    for (int t = 0; t < 5; ++t) {
        hbv[t] = *(const bf16x8*)&sh2[bi * 328 + ci * 40 + t * 8];
#pragma unroll
        for (int e = 0; e < 8; ++e) {
            const int idx = t * 8 + e;
            const int j = idx / 5;
            float gq = bf2f(hbv[t][e]);
            su[j] += gq;
            sq[j] = fmaf(gq, gq, sq[j]);
        }
    }
    bf16x8* dst = (bf16x8*)(H + ((size_t)s * B_ + b) * KDIM + ci * 40);
#pragma unroll
    for (int t = 0; t < 5; ++t) dst[t] = hbv[t];

#pragma unroll
    for (int j = 0; j < 8; ++j) {
        su[j] += __shfl_down(su[j], 32); sq[j] += __shfl_down(sq[j], 32);
        su[j] += __shfl_down(su[j], 16); sq[j] += __shfl_down(sq[j], 16);
        su[j] += __shfl_down(su[j], 8);  sq[j] += __shfl_down(sq[j], 8);
    }
    const int wid = tid >> 6;
    if (lane < 8) {
#pragma unroll
        for (int j = 0; j < 8; ++j) {
            sred[wid][lane][j] = su[j];
            sred[wid][lane][8 + j] = sq[j];
        }
    }
    __syncthreads();
    if (tid < 128) {
        const int which = tid >> 6;
        const int c2 = tid & 63;
        const int rci = c2 >> 3, rj = c2 & 7;
        float v = sred[0][rci][which * 8 + rj] + sred[1][rci][which * 8 + rj]
                + sred[2][rci][which * 8 + rj] + sred[3][rci][which * 8 + rj];
        atomicAdd(&stats[(s * D2 + c2) * 2 + which], v);
    }
}

// ---------------------------------------------------------------------------
__global__ void k_stats(const float* __restrict__ stats,
                        const float* __restrict__ gamma, const float* __restrict__ beta,
                        float* __restrict__ af, float* __restrict__ cf)
{
    int i = threadIdx.x;
    if (i < S_ * D2) {
        const float n = (float)B_ * (float)L_;
        float su = stats[i * 2 + 0], sq = stats[i * 2 + 1];
        float mean = su / n;
        float var = sq / n - mean * mean;
        float rstd = rsqrtf(var + EPS_);
        float a = gamma[i] * rstd;
        af[i] = a;
        cf[i] = beta[i] - mean * a;
    }
}

// ---------------------------------------------------------------------------
// k_fold v2: emit Wp in [s][kstep(10)][quad(4)][col(576)][8] bf16 layout so a
// k_gemm B-fragment load is 4 contiguous 256B segments per wave (was 16x64B).
// ---------------------------------------------------------------------------
__global__ __launch_bounds__(64) void k_fold(
    const float* __restrict__ wl, const float* __restrict__ bl,
    const float* __restrict__ af, const float* __restrict__ cf,
    __hip_bfloat16* __restrict__ Wp, float* __restrict__ blp)
{
    const int row = blockIdx.x;
    const int s = row / OUT_PAD, o = row % OUT_PAD;
    const int lane = threadIdx.x;
    short* Wb = (short*)Wp + (size_t)s * 40 * 576 * 8;   // s plane

    if (o >= OUT_N) {
#pragma unroll
        for (int t = 0; t < 5; ++t) {
            const int k = lane * 5 + t;
            const int idx = (((k >> 5) * 4 + ((k >> 3) & 3)) * 576 + o) * 8 + (k & 7);
            Wb[idx] = f2bf(0.f);
        }
        if (lane == 0) blp[row] = 0.f;
        return;
    }
    const float* wsrc = wl + ((size_t)s * OUT_N + o) * KDIM;
    const float a = af[s * D2 + lane];
    const float c = cf[s * D2 + lane];
    float bacc = 0.f;
#pragma unroll
    for (int t = 0; t < 5; ++t) {
        const int k = lane * 5 + t;
        float wv = wsrc[k];
        const int idx = (((k >> 5) * 4 + ((k >> 3) & 3)) * 576 + o) * 8 + (k & 7);
        Wb[idx] = f2bf(wv * a);
        bacc = fmaf(wv, c, bacc);
    }
#pragma unroll
    for (int off = 32; off > 0; off >>= 1) bacc += __shfl_down(bacc, off);
    if (lane == 0) blp[row] = bacc + bl[s * OUT_N + o];
}

// ---------------------------------------------------------------------------
// Kernel 3 v5: full-N blocks, write-coalescing-first GEMM. (unchanged, passing)
// ---------------------------------------------------------------------------
__global__ __launch_bounds__(256, 3) void k_gemm(
    const __hip_bfloat16* __restrict__ H, const __hip_bfloat16* __restrict__ Wp,
    const float* __restrict__ blp, float* __restrict__ out)
{
    const int s    = blockIdx.z;
    const int bm   = blockIdx.x * 32;
    const int tid  = threadIdx.x;
    const int wave = tid >> 6;
    const int lane = tid & 63;
    const int lm   = lane & 15;
    const int quad = lane >> 4;

    __shared__ __align__(16) short sA[32 * 320];   // [row][16B-chunk, XOR-swizzled]

    const short* Hs = (const short*)H + (size_t)s * B_ * KDIM;

#pragma unroll
    for (int i = 0; i < 5; ++i) {
        const int f = i * 256 + tid;              // 0..1279
        const int row = f / 40, cslot = f % 40;
        const int cg = (cslot & ~7) | ((cslot & 7) ^ (row & 7));
        cp16(&sA[f * 8], Hs + (size_t)(bm + row) * KDIM + cg * 8);
    }
    __syncthreads();   // the only barrier

    const short* Bs = (const short*)Wp + (size_t)s * 40 * 576 * 8;
    const int colw = wave * 144;

    f32x4 acc[2][9];
#pragma unroll
    for (int mt = 0; mt < 2; ++mt)
#pragma unroll
        for (int nt = 0; nt < 9; ++nt) acc[mt][nt] = (f32x4){0.f, 0.f, 0.f, 0.f};

#pragma unroll
    for (int ks = 0; ks < 10; ++ks) {
        bf16x8 bfr[9];
#pragma unroll
        for (int nt = 0; nt < 9; ++nt) {
            bfr[nt] = *(const bf16x8*)(Bs +
                ((size_t)(ks * 4 + quad) * 576 + colw + nt * 16 + lm) * 8);
        }
#pragma unroll
        for (int mt = 0; mt < 2; ++mt) {
            const int row = mt * 16 + lm;
            const int chunk = ks * 4 + quad;
            const int swz = (chunk & ~7) | ((chunk & 7) ^ (row & 7));
            bf16x8 af = *(const bf16x8*)&sA[row * 320 + swz * 8];
#pragma unroll
            for (int nt = 0; nt < 9; ++nt)
                acc[mt][nt] = __builtin_amdgcn_mfma_f32_16x16x32_bf16(
                    af, bfr[nt], acc[mt][nt], 0, 0, 0);
        }
    }

    float bias[9];
#pragma unroll
    for (int nt = 0; nt < 9; ++nt) bias[nt] = blp[s * OUT_PAD + colw + nt * 16 + lm];

#pragma unroll
    for (int mt = 0; mt < 2; ++mt) {
#pragma unroll
        for (int r = 0; r < 4; ++r) {
            const int row = bm + mt * 16 + quad * 4 + r;
            float* orow = out + ((size_t)row * S_ + s) * OUT_N;
#pragma unroll
            for (int nt = 0; nt < 9; ++nt) {
                const int col = colw + nt * 16 + lm;
                if (col < OUT_N) orow[col] = acc[mt][nt][r] + bias[nt];
            }
        }
    }
}

// ---------------------------------------------------------------------------
extern "C" void kernel_launch(void* const* d_in, const int* in_sizes, int n_in,
                              void* d_out, int out_size, void* d_ws, size_t ws_size,
                              hipStream_t stream) {
    const float* x     = (const float*)d_in[0];
    const float* w1    = (const float*)d_in[1];
    const float* b1    = (const float*)d_in[2];
    const float* w2    = (const float*)d_in[3];
    const float* b2    = (const float*)d_in[4];
    const float* gamma = (const float*)d_in[5];
    const float* beta  = (const float*)d_in[6];
    const float* wl    = (const float*)d_in[7];
    const float* bl    = (const float*)d_in[8];
    float* out = (float*)d_out;

    char* ws = (char*)d_ws;
    __hip_bfloat16* H = (__hip_bfloat16*)ws;
    size_t offH = (size_t)S_ * B_ * KDIM * sizeof(__hip_bfloat16);
    float* stats = (float*)(ws + offH);
    float* af = stats + S_ * D2 * 2;
    float* cf = af + S_ * D2;
    __hip_bfloat16* Wp = (__hip_bfloat16*)(cf + S_ * D2);
    float* blp = (float*)((char*)Wp + (size_t)S_ * OUT_PAD * KDIM * sizeof(__hip_bfloat16));

    hipMemsetAsync(stats, 0, (size_t)S_ * D2 * 2 * sizeof(float), stream);

    k_feat<<<dim3(B_ / 32, S_), 256, 0, stream>>>(x, w1, b1, w2, b2, H, stats);
    k_stats<<<1, 256, 0, stream>>>(stats, gamma, beta, af, cf);
    k_fold<<<S_ * OUT_PAD, 64, 0, stream>>>(wl, bl, af, cf, Wp, blp);
    k_gemm<<<dim3(B_ / 32, 1, S_), 256, 0, stream>>>(H, Wp, blp, out);
}